// Round 3
// baseline (666.589 us; speedup 1.0000x reference)
//
#include <hip/hip_runtime.h>
#include <stdint.h>

#define HB 8
#define HL 128
#define HV 50257
#define HE 768
#define HM 400
#define HMT 800
#define HBL (HB*HL)
#define NTILES 393   // ceil(HV/128)

typedef __attribute__((ext_vector_type(4))) float f32x4;
typedef __attribute__((ext_vector_type(8))) short bf16x8;
typedef unsigned short u16;

struct u16x4 { u16 x, y, z, w; };

__device__ __forceinline__ u16 f2bf(float x){
  union { float f; uint32_t u; } v; v.f = x;
  uint32_t r = v.u + 0x7fffu + ((v.u >> 16) & 1u);
  return (u16)(r >> 16);
}

// ---- big conversion (wte) ---------------------------------------------------
__global__ __launch_bounds__(256) void cvt4_k(const float* __restrict__ src,
                                              u16* __restrict__ dst, long n4){
  long i = (long)blockIdx.x * 256 + threadIdx.x;
  long stride = (long)gridDim.x * 256;
  for (; i < n4; i += stride) {
    const float4 x = ((const float4*)src)[i];
    u16x4 y; y.x = f2bf(x.x); y.y = f2bf(x.y); y.z = f2bf(x.z); y.w = f2bf(x.w);
    ((u16x4*)dst)[i] = y;
  }
}

// ---- fused small preprocessing: hid, rel, Wr1, Wt, wcat --------------------
__global__ __launch_bounds__(256) void prep_k(const float* __restrict__ hs,
    const float* __restrict__ rel, const float* __restrict__ Wr1src,
    const float* __restrict__ Wtsrc, const float* __restrict__ Ws1,
    const float* __restrict__ Wn1, u16* __restrict__ hid_b, u16* __restrict__ rel_b,
    u16* __restrict__ wr1, u16* __restrict__ wt_b, u16* __restrict__ wcat){
  const int b = blockIdx.x, t = threadIdx.x;
  if (b < 768) {
    int i = b*256 + t;
    float4 x = ((const float4*)hs)[i];
    u16x4 y; y.x=f2bf(x.x); y.y=f2bf(x.y); y.z=f2bf(x.z); y.w=f2bf(x.w);
    ((u16x4*)hid_b)[i] = y;
  } else if (b < 798) {
    int i = (b-768)*256 + t;
    float4 x = ((const float4*)rel)[i];
    u16x4 y; y.x=f2bf(x.x); y.y=f2bf(x.y); y.z=f2bf(x.z); y.w=f2bf(x.w);
    ((u16x4*)rel_b)[i] = y;
  } else if (b < 1374) {
    int i = (b-798)*256 + t;
    float4 x = ((const float4*)Wr1src)[i];
    u16x4 y; y.x=f2bf(x.x); y.y=f2bf(x.y); y.z=f2bf(x.z); y.w=f2bf(x.w);
    ((u16x4*)wr1)[i] = y;
  } else if (b < 3102) {
    int i = (b-1374)*256 + t;
    float4 x = ((const float4*)Wtsrc)[i];
    u16x4 y; y.x=f2bf(x.x); y.y=f2bf(x.y); y.z=f2bf(x.z); y.w=f2bf(x.w);
    ((u16x4*)wt_b)[i] = y;
  } else {
    int i = (b-3102)*256 + t;
    int e = i / HE, k = i - e*HE;
    wcat[(long)e*(2*HE) + k]      = f2bf(Ws1[i]);
    wcat[(long)e*(2*HE) + HE + k] = f2bf(Wn1[i]);
  }
}

// ---- fused GCN scatter + anode build (per batch x 16-col chunk) ------------
__global__ __launch_bounds__(256) void gcn_scatter_k(const float* __restrict__ wte,
    const float* __restrict__ rel, const int* __restrict__ cids,
    const int* __restrict__ rids, const int* __restrict__ head,
    const int* __restrict__ tail, u16* __restrict__ An){
  const int ch = blockIdx.x % 48;
  const int b  = blockIdx.x / 48;
  const int e0 = ch * 16;
  __shared__ float cw[HM][17];
  __shared__ float upd[HM][17];
  __shared__ float relc[40][17];
  __shared__ float cnt[HM];
  const int tid = threadIdx.x;

  for (int idx = tid; idx < HM*16; idx += 256) {
    int m = idx >> 4, e = idx & 15;
    cw[m][e] = wte[(long)cids[b*HM+m]*HE + e0 + e];
    upd[m][e] = 0.f;
  }
  for (int idx = tid; idx < 40*16; idx += 256) {
    int r = idx >> 4, e = idx & 15;
    relc[r][e] = rel[r*HE + e0 + e];
  }
  for (int m = tid; m < HM; m += 256) cnt[m] = 0.f;
  __syncthreads();

  for (int j = tid; j < HMT; j += 256) {
    int h = head[b*HMT+j], t = tail[b*HMT+j], r = rids[b*HMT+j];
    atomicAdd(&cnt[t], 1.f);
    atomicAdd(&cnt[h], 1.f);
    #pragma unroll
    for (int e = 0; e < 16; ++e) {
      float rv = relc[r][e];
      atomicAdd(&upd[t][e], cw[h][e] - rv);
      atomicAdd(&upd[h][e], cw[t][e] - rv);
    }
  }
  __syncthreads();

  for (int idx = tid; idx < HM*16; idx += 256) {
    int m = idx >> 4, e = idx & 15;
    float ic = 1.f / fmaxf(cnt[m], 1.f);
    u16* dst = An + ((long)b*HM + m) * (2*HE);
    dst[e0 + e]      = f2bf(cw[m][e]);
    dst[HE + e0 + e] = f2bf(upd[m][e] * ic);
  }
}

// ---- broadcast relW2 rows into P13[b][800..839] ----------------------------
__global__ __launch_bounds__(256) void bcast_relw2_k(const u16* __restrict__ relW2,
    u16* __restrict__ P13){
  int i = blockIdx.x*256 + threadIdx.x;
  if (i >= HB*40*HE) return;
  int b = i / (40*HE), rem = i - b*40*HE;
  P13[(long)b*840*HE + (long)800*HE + rem] = relW2[rem];
}

// ---- generic MFMA GEMM: C[M,N] = act(A[M,K] @ B[N,K]^T) ---------------------
// 128x128 tile, BK=32, 4 waves 2x2, 16x16x32 bf16 MFMA, global_load_lds staging.
// SWZ=1: 1-D grid 3144 = 8 XCD chunks of 393; m-tile fast within chunk.
template<int ACT, int OUTBF16, int ROWSUM, int SWZ>
__global__ __launch_bounds__(256) void gemm_bt(
    const u16* __restrict__ A, const u16* __restrict__ Bm, void* __restrict__ Cout,
    float* __restrict__ rowpart,
    int Mdim, int Ndim, int Kdim, int lda, int ldb, int ldc,
    long Abs, long Bbs, long Cbs)
{
  __shared__ alignas(16) u16 Asm[128*32];
  __shared__ alignas(16) u16 Bsm[128*32];
  int mtile, ntile, bz;
  if (SWZ) {
    const int wg = (blockIdx.x & 7) * NTILES + (blockIdx.x >> 3);
    mtile = wg & 7; ntile = wg >> 3; bz = 0;
  } else {
    mtile = blockIdx.x; ntile = blockIdx.y; bz = blockIdx.z;
  }
  const u16* Ab = A + (long)bz * Abs;
  const u16* Bb = Bm + (long)bz * Bbs;
  const int m0 = mtile * 128;
  const int n0 = ntile * 128;
  const int tid = threadIdx.x;
  const int lane = tid & 63;
  const int wid = tid >> 6;
  const int wr = wid >> 1, wc = wid & 1;

  f32x4 acc[4][4] = {};

  for (int k0 = 0; k0 < Kdim; k0 += 32) {
    #pragma unroll
    for (int i = 0; i < 2; ++i) {
      const int c = wid*128 + i*64 + lane;
      const int row = c >> 2, seg = c & 3;
      int ra = m0 + row; if (ra > Mdim-1) ra = Mdim-1;
      const u16* ga = Ab + (long)ra * lda + k0 + seg*8;
      __builtin_amdgcn_global_load_lds(
          (const __attribute__((address_space(1))) void*)ga,
          (__attribute__((address_space(3))) void*)&Asm[(wid*128 + i*64)*8], 16, 0, 0);
      int rn = n0 + row; if (rn > Ndim-1) rn = Ndim-1;
      const u16* gb = Bb + (long)rn * ldb + k0 + seg*8;
      __builtin_amdgcn_global_load_lds(
          (const __attribute__((address_space(1))) void*)gb,
          (__attribute__((address_space(3))) void*)&Bsm[(wid*128 + i*64)*8], 16, 0, 0);
    }
    __syncthreads();
    const int frow = lane & 15;
    const int koff = (lane >> 4) * 8;
    bf16x8 af[4], bfr[4];
    #pragma unroll
    for (int mi = 0; mi < 4; ++mi)
      af[mi] = *(const bf16x8*)&Asm[(wr*64 + mi*16 + frow)*32 + koff];
    #pragma unroll
    for (int ni = 0; ni < 4; ++ni)
      bfr[ni] = *(const bf16x8*)&Bsm[(wc*64 + ni*16 + frow)*32 + koff];
    #pragma unroll
    for (int mi = 0; mi < 4; ++mi)
      #pragma unroll
      for (int ni = 0; ni < 4; ++ni)
        acc[mi][ni] = __builtin_amdgcn_mfma_f32_16x16x32_bf16(af[mi], bfr[ni], acc[mi][ni], 0, 0, 0);
    __syncthreads();
  }

  const long cb = (long)bz * Cbs;
  const int cr0 = m0 + wr*64 + ((lane >> 4) * 4);
  const int cc0 = n0 + wc*64 + (lane & 15);
  #pragma unroll
  for (int mi = 0; mi < 4; ++mi) {
    #pragma unroll
    for (int ni = 0; ni < 4; ++ni) {
      const int col = cc0 + ni*16;
      if (col < Ndim) {
        #pragma unroll
        for (int r = 0; r < 4; ++r) {
          const int rowi = cr0 + mi*16 + r;
          if (rowi < Mdim) {
            float v = acc[mi][ni][r];
            if (ACT == 1) v = fmaxf(v, 0.f);
            if (OUTBF16) ((u16*)Cout)[cb + (long)rowi*ldc + col] = f2bf(v);
            else        ((float*)Cout)[cb + (long)rowi*ldc + col] = v;
          }
        }
      }
    }
  }
  if (ROWSUM) {
    // atomic-free: per-block row sums of exp(logit) -> rowpart[ntile][1024]
    float* rs = (float*)Asm;   // LDS reuse, free after last barrier
    #pragma unroll
    for (int mi = 0; mi < 4; ++mi) {
      #pragma unroll
      for (int r = 0; r < 4; ++r) {
        float s = 0.f;
        #pragma unroll
        for (int ni = 0; ni < 4; ++ni) {
          const int col = cc0 + ni*16;
          s += (col < Ndim) ? __expf(acc[mi][ni][r]) : 0.f;
        }
        s += __shfl_xor(s, 8); s += __shfl_xor(s, 4);
        s += __shfl_xor(s, 2); s += __shfl_xor(s, 1);
        if ((lane & 15) == 0)
          rs[wc*128 + wr*64 + mi*16 + ((lane >> 4) << 2) + r] = s;
      }
    }
    __syncthreads();
    if (tid < 128)
      rowpart[(long)ntile*HBL + m0 + tid] = rs[tid] + rs[128 + tid];
  }
}

// ---- reduce rowsum partials over n-tiles ------------------------------------
__global__ __launch_bounds__(256) void redsum_k(const float* __restrict__ rowpart,
    float* __restrict__ rowsum){
  int r = blockIdx.x*256 + threadIdx.x;
  if (r < HBL) {
    float s = 0.f;
    for (int t = 0; t < NTILES; ++t) s += rowpart[(long)t*HBL + r];
    rowsum[r] = s;
  }
}

// ---- multi-hop + gate: factored triple_prob, hops, softmax over M ----------
__global__ __launch_bounds__(256) void multihop_k(const float* __restrict__ scores,
    const float* __restrict__ hs, const float* __restrict__ gw,
    const float* __restrict__ gb,
    const int* __restrict__ head, const int* __restrict__ tail,
    const int* __restrict__ rids, const int* __restrict__ labels,
    const int* __restrict__ dist, float* __restrict__ gatev,
    float* __restrict__ cprob){
  const int bl = blockIdx.x;
  const int b = bl >> 7;
  const int tid = threadIdx.x;
  const int lane = tid & 63, wid = tid >> 6;
  __shared__ float srow[840];
  __shared__ float tp[HMT];
  __shared__ float ns[HM], sacc[HM], tot[HM], invc[HM], dec[HM];
  __shared__ float red[16];
  __shared__ float gred[4];
  const int* hb = head + b*HMT;
  const int* tb = tail + b*HMT;
  const int* rb = rids + b*HMT;
  const int* lb = labels + b*HMT;
  const float* sr = scores + (long)bl * 840;

  // gate dot-product
  float gs = 0.f;
  for (int e = tid; e < HE; e += 256) gs += hs[(long)bl*HE + e] * gw[e];
  for (int o = 32; o; o >>= 1) gs += __shfl_down(gs, o);
  if (lane == 0) gred[wid] = gs;

  for (int i = tid; i < 840; i += 256) srow[i] = sr[i];
  for (int m = tid; m < HM; m += 256) {
    int d = dist[b*HM + m];
    float im = (d == 0) ? 1.f : 0.f;
    ns[m] = im; tot[m] = im * -100000.f;
    dec[m] = (d == 0) ? 1.f : ((d == 1) ? 0.8f : 0.64f);
    sacc[m] = 0.f; invc[m] = 0.f;
  }
  __syncthreads();
  if (tid == 0)
    gatev[bl] = 1.f / (1.f + __expf(-(gred[0]+gred[1]+gred[2]+gred[3] + gb[0])));
  for (int j = tid; j < HMT; j += 256) {
    atomicAdd(&invc[tb[j]], 1.f);
    float x = srow[hb[j]] + srow[400 + tb[j]] + srow[800 + rb[j]];
    tp[j] = (lb[j] == -1) ? 0.f : 1.f / (1.f + __expf(-x));
  }
  __syncthreads();
  for (int m = tid; m < HM; m += 256) invc[m] = 1.f / fmaxf(invc[m], 1.f);
  __syncthreads();

  for (int hop = 0; hop < 2; ++hop) {
    for (int j = tid; j < HMT; j += 256) {
      float u = ns[hb[j]] * 0.8f + tp[j];
      atomicAdd(&sacc[tb[j]], u);
    }
    __syncthreads();
    for (int m = tid; m < HM; m += 256) {
      float v = sacc[m] * invc[m];
      ns[m] = v; tot[m] += v * dec[m]; sacc[m] = 0.f;
    }
    __syncthreads();
  }

  float lmx = -3.4e38f;
  for (int m = tid; m < HM; m += 256) lmx = fmaxf(lmx, tot[m]);
  for (int o = 32; o; o >>= 1) lmx = fmaxf(lmx, __shfl_down(lmx, o));
  if (lane == 0) red[wid] = lmx;
  __syncthreads();
  float gmx = fmaxf(fmaxf(red[0], red[1]), fmaxf(red[2], red[3]));
  float ls = 0.f;
  for (int m = tid; m < HM; m += 256) ls += __expf(tot[m] - gmx);
  for (int o = 32; o; o >>= 1) ls += __shfl_down(ls, o);
  if (lane == 0) red[8 + wid] = ls;
  __syncthreads();
  float inv = 1.f / (red[8] + red[9] + red[10] + red[11]);
  float* outrow = cprob + (long)bl * HM;
  for (int m = tid; m < HM; m += 256) outrow[m] = __expf(tot[m] - gmx) * inv;
}

// ---- final blend, in-place over d_out (logits -> probs) --------------------
__global__ __launch_bounds__(256) void finalize_k(float* __restrict__ out,
    const float* __restrict__ rsum, const float* __restrict__ gate,
    const float* __restrict__ cprob, const int* __restrict__ vmap,
    const int* __restrict__ mmask){
  const long base = ((long)blockIdx.x * 256 + threadIdx.x) * 4;
  float4 x = *(float4*)&out[base];
  float r4[4];
  const float* xs = (const float*)&x;
  #pragma unroll
  for (int i = 0; i < 4; ++i) {
    unsigned idx = (unsigned)base + i;
    unsigned r = idx / 50257u;
    unsigned v = idx - r * 50257u;
    float g = gate[r];
    float lm = __expf(xs[i]) / rsum[r];
    float cp = (mmask[v] != 0) ? cprob[r*400u + vmap[v]] : 0.f;
    r4[i] = g * cp + (1.f - g) * lm;
  }
  float4 y; y.x = r4[0]; y.y = r4[1]; y.z = r4[2]; y.w = r4[3];
  *(float4*)&out[base] = y;
}

// ---------------------------------------------------------------------------
extern "C" void kernel_launch(void* const* d_in, const int* in_sizes, int n_in,
                              void* d_out, int out_size, void* d_ws, size_t ws_size,
                              hipStream_t stream)
{
  const float* hs   = (const float*)d_in[0];
  const float* wte  = (const float*)d_in[1];
  const float* rel  = (const float*)d_in[2];
  const float* Ws   = (const float*)d_in[3];
  const float* Wn   = (const float*)d_in[4];
  const float* Wr   = (const float*)d_in[5];
  const float* Wt   = (const float*)d_in[6];
  const float* gw   = (const float*)d_in[7];
  const float* gb   = (const float*)d_in[8];
  const int* cids   = (const int*)d_in[9];
  const int* rids   = (const int*)d_in[10];
  const int* head   = (const int*)d_in[11];
  const int* tail   = (const int*)d_in[12];
  const int* labels = (const int*)d_in[13];
  const int* dist   = (const int*)d_in[14];
  const int* vmap   = (const int*)d_in[15];
  const int* mmask  = (const int*)d_in[16];
  float* out = (float*)d_out;

  char* ws = (char*)d_ws;
  size_t o = 0;
  auto alloc = [&](size_t bytes) -> char* {
    char* p = ws + o; o = (o + bytes + 255) & ~(size_t)255; return p;
  };
  u16* wte_b = (u16*)alloc((size_t)HV*HE*2);          // 77.2 MB
  u16* hid_b = (u16*)alloc((size_t)HBL*HE*2);         // 1.6 MB
  u16* wcat  = (u16*)alloc((size_t)HE*2*HE*2);        // 2.4 MB
  u16* wr1   = (u16*)alloc((size_t)HE*HE*2);          // 1.2 MB
  u16* wt_b  = (u16*)alloc((size_t)HE*3*HE*2);        // 3.5 MB
  u16* rel_b = (u16*)alloc((size_t)40*HE*2);
  u16* anode = (u16*)alloc((size_t)HB*HM*2*HE*2);     // 9.8 MB
  u16* nodeb = (u16*)alloc((size_t)HB*HM*HE*2);       // 4.9 MB
  u16* relWr = (u16*)alloc((size_t)40*HE*2);
  u16* relW2 = (u16*)alloc((size_t)40*HE*2);
  u16* P13   = (u16*)alloc((size_t)HB*840*HE*2);      // 10.3 MB
  float* scores  = (float*)alloc((size_t)HB*HL*840*4);// 3.4 MB
  float* cprob   = (float*)alloc((size_t)HB*HL*HM*4); // 1.6 MB
  float* rowpart = (float*)alloc((size_t)NTILES*HBL*4);// 1.6 MB
  float* rowsum  = (float*)alloc(HBL*4);
  float* gatev   = (float*)alloc(HBL*4);
  (void)ws_size; (void)in_sizes; (void)n_in; (void)out_size;

  // small preprocessing (fused)
  prep_k<<<5406, 256, 0, stream>>>(hs, rel, Wr + (size_t)HE*HE, Wt,
      Ws + (size_t)HE*HE, Wn + (size_t)HE*HE, hid_b, rel_b, wr1, wt_b, wcat);

  // fused GCN scatter -> anode (bf16 [8][400][1536])
  gcn_scatter_k<<<HB*48, 256, 0, stream>>>(wte, rel, cids, rids, head, tail, anode);

  // node = relu(anode @ wcat^T): batched, M=400, N=768, K=1536
  gemm_bt<1,1,0,0><<<dim3(4,6,8), 256, 0, stream>>>(anode, wcat, nodeb, nullptr,
      HM, HE, 2*HE, 2*HE, 2*HE, HE, (long)HM*2*HE, 0, (long)HM*HE);
  // relWr = rel @ Wr1^T  (40x768, K=768)
  gemm_bt<0,1,0,0><<<dim3(1,6,1), 256, 0, stream>>>(rel_b, wr1, relWr, nullptr,
      40, HE, HE, HE, HE, HE, 0, 0, 0);
  // relW2 = relWr @ Wt2^T (Wt cols 768..1535, ldb=2304)
  gemm_bt<0,1,0,0><<<dim3(1,6,1), 256, 0, stream>>>(relWr, wt_b + HE, relW2, nullptr,
      40, HE, HE, HE, 3*HE, HE, 0, 0, 0);
  // P1 = node @ Wt1^T -> P13 rows 0..399 ; P3 = node @ Wt3^T -> rows 400..799
  gemm_bt<0,1,0,0><<<dim3(4,6,8), 256, 0, stream>>>(nodeb, wt_b, P13, nullptr,
      HM, HE, HE, HE, 3*HE, HE, (long)HM*HE, 0, (long)840*HE);
  gemm_bt<0,1,0,0><<<dim3(4,6,8), 256, 0, stream>>>(nodeb, wt_b + 2*HE, P13 + (long)HM*HE, nullptr,
      HM, HE, HE, HE, 3*HE, HE, (long)HM*HE, 0, (long)840*HE);
  bcast_relw2_k<<<(HB*40*HE+255)/256, 256, 0, stream>>>(relW2, P13);
  // scores = hid @ P13^T: batched, M=128, N=840, K=768
  gemm_bt<0,0,0,0><<<dim3(1,7,8), 256, 0, stream>>>(hid_b, P13, scores, nullptr,
      HL, 840, HE, HE, HE, 840, (long)HL*HE, (long)840*HE, (long)HL*840);

  // wte -> bf16 right before the big GEMM (L3 residency)
  cvt4_k<<<4096, 256, 0, stream>>>(wte, wte_b, (long)HV*HE/4);

  // logits = hid @ wte^T -> d_out, fused atomic-free rowsum partials.
  // 1-D grid 3144 = 8 XCDs x 393 n-tiles; m-fast within each XCD chunk.
  gemm_bt<0,0,1,1><<<3144, 256, 0, stream>>>(hid_b, wte_b, out, rowpart,
      HBL, HV, HE, HE, HE, HV, 0, 0, 0);
  redsum_k<<<4, 256, 0, stream>>>(rowpart, rowsum);

  multihop_k<<<HBL, 256, 0, stream>>>(scores, hs, gw, gb, head, tail, rids,
      labels, dist, gatev, cprob);
  finalize_k<<<HV, 256, 0, stream>>>(out, rowsum, gatev, cprob, vmap, mmask);
}

// Round 4
// 539.244 us; speedup vs baseline: 1.2362x; 1.2362x over previous
//
#include <hip/hip_runtime.h>
#include <stdint.h>

#define HB 8
#define HL 128
#define HV 50257
#define HE 768
#define HM 400
#define HMT 800
#define HBL (HB*HL)
#define NTILES 393   // ceil(HV/128)
#define ELD 50272    // padded bf16-exp leading dim (mult of 16)

typedef __attribute__((ext_vector_type(4))) float f32x4;
typedef __attribute__((ext_vector_type(8))) short bf16x8;
typedef unsigned short u16;

struct u16x4 { u16 x, y, z, w; };

__device__ __forceinline__ u16 f2bf(float x){
  union { float f; uint32_t u; } v; v.f = x;
  uint32_t r = v.u + 0x7fffu + ((v.u >> 16) & 1u);
  return (u16)(r >> 16);
}
__device__ __forceinline__ float bf2f(u16 b){
  union { uint32_t u; float f; } v; v.u = ((uint32_t)b) << 16;
  return v.f;
}
__device__ __forceinline__ void glds(const u16* g, const u16* l){
  __builtin_amdgcn_global_load_lds(
      (const __attribute__((address_space(1))) void*)g,
      (__attribute__((address_space(3))) void*)l, 16, 0, 0);
}

// ---- big conversion (wte) ---------------------------------------------------
__global__ __launch_bounds__(256) void cvt4_k(const float* __restrict__ src,
                                              u16* __restrict__ dst, long n4){
  long i = (long)blockIdx.x * 256 + threadIdx.x;
  long stride = (long)gridDim.x * 256;
  for (; i < n4; i += stride) {
    const float4 x = ((const float4*)src)[i];
    u16x4 y; y.x = f2bf(x.x); y.y = f2bf(x.y); y.z = f2bf(x.z); y.w = f2bf(x.w);
    ((u16x4*)dst)[i] = y;
  }
}

// ---- fused small preprocessing: hid, rel, Wr1, Wt, wcat --------------------
__global__ __launch_bounds__(256) void prep_k(const float* __restrict__ hs,
    const float* __restrict__ rel, const float* __restrict__ Wr1src,
    const float* __restrict__ Wtsrc, const float* __restrict__ Ws1,
    const float* __restrict__ Wn1, u16* __restrict__ hid_b, u16* __restrict__ rel_b,
    u16* __restrict__ wr1, u16* __restrict__ wt_b, u16* __restrict__ wcat){
  const int b = blockIdx.x, t = threadIdx.x;
  if (b < 768) {
    int i = b*256 + t;
    float4 x = ((const float4*)hs)[i];
    u16x4 y; y.x=f2bf(x.x); y.y=f2bf(x.y); y.z=f2bf(x.z); y.w=f2bf(x.w);
    ((u16x4*)hid_b)[i] = y;
  } else if (b < 798) {
    int i = (b-768)*256 + t;
    float4 x = ((const float4*)rel)[i];
    u16x4 y; y.x=f2bf(x.x); y.y=f2bf(x.y); y.z=f2bf(x.z); y.w=f2bf(x.w);
    ((u16x4*)rel_b)[i] = y;
  } else if (b < 1374) {
    int i = (b-798)*256 + t;
    float4 x = ((const float4*)Wr1src)[i];
    u16x4 y; y.x=f2bf(x.x); y.y=f2bf(x.y); y.z=f2bf(x.z); y.w=f2bf(x.w);
    ((u16x4*)wr1)[i] = y;
  } else if (b < 3102) {
    int i = (b-1374)*256 + t;
    float4 x = ((const float4*)Wtsrc)[i];
    u16x4 y; y.x=f2bf(x.x); y.y=f2bf(x.y); y.z=f2bf(x.z); y.w=f2bf(x.w);
    ((u16x4*)wt_b)[i] = y;
  } else {
    int i = (b-3102)*256 + t;
    int e = i / HE, k = i - e*HE;
    wcat[(long)e*(2*HE) + k]      = f2bf(Ws1[i]);
    wcat[(long)e*(2*HE) + HE + k] = f2bf(Wn1[i]);
  }
}

// ---- fused GCN scatter + anode build (per batch x 16-col chunk) ------------
__global__ __launch_bounds__(256) void gcn_scatter_k(const float* __restrict__ wte,
    const float* __restrict__ rel, const int* __restrict__ cids,
    const int* __restrict__ rids, const int* __restrict__ head,
    const int* __restrict__ tail, u16* __restrict__ An){
  const int ch = blockIdx.x % 48;
  const int b  = blockIdx.x / 48;
  const int e0 = ch * 16;
  __shared__ float cw[HM][17];
  __shared__ float upd[HM][17];
  __shared__ float relc[40][17];
  __shared__ float cnt[HM];
  const int tid = threadIdx.x;

  for (int idx = tid; idx < HM*16; idx += 256) {
    int m = idx >> 4, e = idx & 15;
    cw[m][e] = wte[(long)cids[b*HM+m]*HE + e0 + e];
    upd[m][e] = 0.f;
  }
  for (int idx = tid; idx < 40*16; idx += 256) {
    int r = idx >> 4, e = idx & 15;
    relc[r][e] = rel[r*HE + e0 + e];
  }
  for (int m = tid; m < HM; m += 256) cnt[m] = 0.f;
  __syncthreads();

  for (int j = tid; j < HMT; j += 256) {
    int h = head[b*HMT+j], t = tail[b*HMT+j], r = rids[b*HMT+j];
    atomicAdd(&cnt[t], 1.f);
    atomicAdd(&cnt[h], 1.f);
    #pragma unroll
    for (int e = 0; e < 16; ++e) {
      float rv = relc[r][e];
      atomicAdd(&upd[t][e], cw[h][e] - rv);
      atomicAdd(&upd[h][e], cw[t][e] - rv);
    }
  }
  __syncthreads();

  for (int idx = tid; idx < HM*16; idx += 256) {
    int m = idx >> 4, e = idx & 15;
    float ic = 1.f / fmaxf(cnt[m], 1.f);
    u16* dst = An + ((long)b*HM + m) * (2*HE);
    dst[e0 + e]      = f2bf(cw[m][e]);
    dst[HE + e0 + e] = f2bf(upd[m][e] * ic);
  }
}

// ---- generic MFMA GEMM: C[M,N] = act(A[M,K] @ B[N,K]^T) ---------------------
// 128x128 tile, BK=64, XOR-swizzled LDS (16B slot ^ row&7), 4 waves 2x2,
// 16x16x32 bf16 MFMA, global_load_lds (linear dest + inverse-swizzled source).
// BIG=1: 1-D grid 3144 = 8 XCD chunks of 393, exp+bf16(or f32) store + rowpart.
template<int ACT, int OUTBF16, int BIG>
__global__ __launch_bounds__(256) void gemm_bt(
    const u16* __restrict__ A, const u16* __restrict__ Bm, void* __restrict__ Cout,
    float* __restrict__ rowpart,
    int Mdim, int Ndim, int Kdim, int lda, int ldb, int ldc,
    long Abs, long Bbs, long Cbs)
{
  __shared__ alignas(16) u16 Asm[128*64];
  __shared__ alignas(16) u16 Bsm[128*64];
  int mtile, ntile, bz;
  if (BIG) {
    const int wg = (blockIdx.x & 7) * NTILES + (blockIdx.x >> 3);
    mtile = wg & 7; ntile = wg >> 3; bz = 0;
  } else {
    mtile = blockIdx.x; ntile = blockIdx.y; bz = blockIdx.z;
  }
  const u16* Ab = A + (long)bz * Abs;
  const u16* Bb = Bm + (long)bz * Bbs;
  const int m0 = mtile * 128;
  const int n0 = ntile * 128;
  const int tid = threadIdx.x;
  const int lane = tid & 63;
  const int wid = tid >> 6;
  const int wr = wid >> 1, wc = wid & 1;
  const int srw = lane >> 3;      // row within 8-row chunk
  const int sl  = lane & 7;       // 16B slot within 128B row

  f32x4 acc[4][4] = {};

  for (int k0 = 0; k0 < Kdim; k0 += 64) {
    #pragma unroll
    for (int i = 0; i < 4; ++i) {
      const int c = i*4 + wid;                 // chunk 0..15 (8 rows each)
      const int row = c*8 + srw;               // 0..127
      const int koff = k0 + ((sl ^ srw) * 8);  // inverse-swizzled source
      int ra = m0 + row; if (ra > Mdim-1) ra = Mdim-1;
      glds(Ab + (long)ra * lda + koff, &Asm[c*512]);
      int rn = n0 + row; if (rn > Ndim-1) rn = Ndim-1;
      glds(Bb + (long)rn * ldb + koff, &Bsm[c*512]);
    }
    __syncthreads();
    #pragma unroll
    for (int kk = 0; kk < 2; ++kk) {
      bf16x8 af[4], bfr[4];
      #pragma unroll
      for (int mi = 0; mi < 4; ++mi) {
        const int R = wr*64 + mi*16 + (lane & 15);
        af[mi] = *(const bf16x8*)&Asm[R*64 + (((kk*4 + (lane>>4)) ^ (R & 7)) * 8)];
      }
      #pragma unroll
      for (int ni = 0; ni < 4; ++ni) {
        const int R = wc*64 + ni*16 + (lane & 15);
        bfr[ni] = *(const bf16x8*)&Bsm[R*64 + (((kk*4 + (lane>>4)) ^ (R & 7)) * 8)];
      }
      #pragma unroll
      for (int mi = 0; mi < 4; ++mi)
        #pragma unroll
        for (int ni = 0; ni < 4; ++ni)
          acc[mi][ni] = __builtin_amdgcn_mfma_f32_16x16x32_bf16(af[mi], bfr[ni], acc[mi][ni], 0, 0, 0);
    }
    __syncthreads();
  }

  const int cr0 = m0 + wr*64 + ((lane >> 4) * 4);
  const int cc0 = n0 + wc*64 + (lane & 15);

  if (BIG) {
    // store exp(logit) (bf16 padded / f32), accumulate row partials (atomic-free)
    float* rs = (float*)Asm;
    #pragma unroll
    for (int mi = 0; mi < 4; ++mi) {
      #pragma unroll
      for (int r = 0; r < 4; ++r) {
        const int rowi = cr0 + mi*16 + r;
        float s = 0.f;
        #pragma unroll
        for (int ni = 0; ni < 4; ++ni) {
          const int col = cc0 + ni*16;
          if (col < Ndim) {
            float e = __expf(acc[mi][ni][r]);
            if (OUTBF16) ((u16*)Cout)[(long)rowi*ELD + col] = f2bf(e);
            else        ((float*)Cout)[(long)rowi*HV + col] = e;
            s += e;
          }
        }
        s += __shfl_xor(s, 8); s += __shfl_xor(s, 4);
        s += __shfl_xor(s, 2); s += __shfl_xor(s, 1);
        if ((lane & 15) == 0)
          rs[wc*128 + wr*64 + mi*16 + ((lane >> 4) << 2) + r] = s;
      }
    }
    __syncthreads();
    if (tid < 128)
      rowpart[(long)(m0 + tid) * NTILES + ntile] = rs[tid] + rs[128 + tid];
    return;
  }

  const long cb = (long)bz * Cbs;
  #pragma unroll
  for (int mi = 0; mi < 4; ++mi) {
    #pragma unroll
    for (int ni = 0; ni < 4; ++ni) {
      const int col = cc0 + ni*16;
      if (col < Ndim) {
        #pragma unroll
        for (int r = 0; r < 4; ++r) {
          const int rowi = cr0 + mi*16 + r;
          if (rowi < Mdim) {
            float v = acc[mi][ni][r];
            if (ACT == 1) v = fmaxf(v, 0.f);
            if (OUTBF16) ((u16*)Cout)[cb + (long)rowi*ldc + col] = f2bf(v);
            else        ((float*)Cout)[cb + (long)rowi*ldc + col] = v;
          }
        }
      }
    }
  }
}

// ---- multi-hop + gate: factored triple_prob, hops, softmax over M ----------
__global__ __launch_bounds__(256) void multihop_k(const float* __restrict__ scores,
    const float* __restrict__ hs, const float* __restrict__ gw,
    const float* __restrict__ gb,
    const int* __restrict__ head, const int* __restrict__ tail,
    const int* __restrict__ rids, const int* __restrict__ labels,
    const int* __restrict__ dist, float* __restrict__ gatev,
    float* __restrict__ cprob){
  const int bl = blockIdx.x;
  const int b = bl >> 7;
  const int tid = threadIdx.x;
  const int lane = tid & 63, wid = tid >> 6;
  __shared__ float srow[840];
  __shared__ float tp[HMT];
  __shared__ float ns[HM], sacc[HM], tot[HM], invc[HM], dec[HM];
  __shared__ float red[16];
  __shared__ float gred[4];
  const int* hb = head + b*HMT;
  const int* tb = tail + b*HMT;
  const int* rb = rids + b*HMT;
  const int* lb = labels + b*HMT;
  const float* sr = scores + (long)bl * 840;

  float gs = 0.f;
  for (int e = tid; e < HE; e += 256) gs += hs[(long)bl*HE + e] * gw[e];
  for (int o = 32; o; o >>= 1) gs += __shfl_down(gs, o);
  if (lane == 0) gred[wid] = gs;

  for (int i = tid; i < 840; i += 256) srow[i] = sr[i];
  for (int m = tid; m < HM; m += 256) {
    int d = dist[b*HM + m];
    float im = (d == 0) ? 1.f : 0.f;
    ns[m] = im; tot[m] = im * -100000.f;
    dec[m] = (d == 0) ? 1.f : ((d == 1) ? 0.8f : 0.64f);
    sacc[m] = 0.f; invc[m] = 0.f;
  }
  __syncthreads();
  if (tid == 0)
    gatev[bl] = 1.f / (1.f + __expf(-(gred[0]+gred[1]+gred[2]+gred[3] + gb[0])));
  for (int j = tid; j < HMT; j += 256) {
    atomicAdd(&invc[tb[j]], 1.f);
    float x = srow[hb[j]] + srow[400 + tb[j]] + srow[800 + rb[j]];
    tp[j] = (lb[j] == -1) ? 0.f : 1.f / (1.f + __expf(-x));
  }
  __syncthreads();
  for (int m = tid; m < HM; m += 256) invc[m] = 1.f / fmaxf(invc[m], 1.f);
  __syncthreads();

  for (int hop = 0; hop < 2; ++hop) {
    for (int j = tid; j < HMT; j += 256) {
      float u = ns[hb[j]] * 0.8f + tp[j];
      atomicAdd(&sacc[tb[j]], u);
    }
    __syncthreads();
    for (int m = tid; m < HM; m += 256) {
      float v = sacc[m] * invc[m];
      ns[m] = v; tot[m] += v * dec[m]; sacc[m] = 0.f;
    }
    __syncthreads();
  }

  float lmx = -3.4e38f;
  for (int m = tid; m < HM; m += 256) lmx = fmaxf(lmx, tot[m]);
  for (int o = 32; o; o >>= 1) lmx = fmaxf(lmx, __shfl_down(lmx, o));
  if (lane == 0) red[wid] = lmx;
  __syncthreads();
  float gmx = fmaxf(fmaxf(red[0], red[1]), fmaxf(red[2], red[3]));
  float ls = 0.f;
  for (int m = tid; m < HM; m += 256) ls += __expf(tot[m] - gmx);
  for (int o = 32; o; o >>= 1) ls += __shfl_down(ls, o);
  if (lane == 0) red[8 + wid] = ls;
  __syncthreads();
  float inv = 1.f / (red[8] + red[9] + red[10] + red[11]);
  float* outrow = cprob + (long)bl * HM;
  for (int m = tid; m < HM; m += 256) outrow[m] = __expf(tot[m] - gmx) * inv;
}

// ---- finalize: fused rowsum reduce + blend ---------------------------------
// grid = HBL * 13 (one row-chunk of 4096 cols per block).
template<int EXPBF>
__global__ __launch_bounds__(256) void finalize_k(const void* __restrict__ expl,
    const float* __restrict__ rowpart, const float* __restrict__ gatev,
    const float* __restrict__ cprob, const int* __restrict__ vmap,
    const int* __restrict__ mmask, float* __restrict__ out){
  const int r = blockIdx.x / 13;
  const int ch = blockIdx.x - r*13;
  const int tid = threadIdx.x;
  __shared__ float red[4];
  float s = 0.f;
  for (int t = tid; t < NTILES; t += 256) s += rowpart[r*NTILES + t];
  for (int o = 32; o; o >>= 1) s += __shfl_down(s, o);
  if ((tid & 63) == 0) red[tid >> 6] = s;
  __syncthreads();
  const float inv = 1.f / (red[0] + red[1] + red[2] + red[3]);
  const float g = gatev[r], g1 = 1.f - g;
  const float* cpr = cprob + r * HM;
  const u16* erb = (const u16*)expl + (long)r * ELD;
  const float* erf = (const float*)expl + (long)r * HV;
  float* orow = out + (long)r * HV;
  #pragma unroll
  for (int it = 0; it < 4; ++it) {
    const int c = ch*4096 + it*1024 + tid*4;
    if (c >= HV) continue;
    if (c + 4 <= HV) {
      float e0, e1, e2, e3;
      if (EXPBF) {
        ushort4 e4 = *(const ushort4*)&erb[c];
        e0 = bf2f(e4.x); e1 = bf2f(e4.y); e2 = bf2f(e4.z); e3 = bf2f(e4.w);
      } else {
        e0 = erf[c]; e1 = erf[c+1]; e2 = erf[c+2]; e3 = erf[c+3];
      }
      int4 vm = *(const int4*)&vmap[c];
      int4 mm = *(const int4*)&mmask[c];
      orow[c]   = (mm.x ? g*cpr[vm.x] : 0.f) + g1*e0*inv;
      orow[c+1] = (mm.y ? g*cpr[vm.y] : 0.f) + g1*e1*inv;
      orow[c+2] = (mm.z ? g*cpr[vm.z] : 0.f) + g1*e2*inv;
      orow[c+3] = (mm.w ? g*cpr[vm.w] : 0.f) + g1*e3*inv;
    } else {
      for (int i = 0; i < 4; ++i) {
        if (c + i < HV) {
          float e = EXPBF ? bf2f(erb[c+i]) : erf[c+i];
          orow[c+i] = (mmask[c+i] ? g*cpr[vmap[c+i]] : 0.f) + g1*e*inv;
        }
      }
    }
  }
}

// ---------------------------------------------------------------------------
extern "C" void kernel_launch(void* const* d_in, const int* in_sizes, int n_in,
                              void* d_out, int out_size, void* d_ws, size_t ws_size,
                              hipStream_t stream)
{
  const float* hs   = (const float*)d_in[0];
  const float* wte  = (const float*)d_in[1];
  const float* rel  = (const float*)d_in[2];
  const float* Ws   = (const float*)d_in[3];
  const float* Wn   = (const float*)d_in[4];
  const float* Wr   = (const float*)d_in[5];
  const float* Wt   = (const float*)d_in[6];
  const float* gw   = (const float*)d_in[7];
  const float* gb   = (const float*)d_in[8];
  const int* cids   = (const int*)d_in[9];
  const int* rids   = (const int*)d_in[10];
  const int* head   = (const int*)d_in[11];
  const int* tail   = (const int*)d_in[12];
  const int* labels = (const int*)d_in[13];
  const int* dist   = (const int*)d_in[14];
  const int* vmap   = (const int*)d_in[15];
  const int* mmask  = (const int*)d_in[16];
  float* out = (float*)d_out;

  char* ws = (char*)d_ws;
  size_t o = 0;
  auto alloc = [&](size_t bytes) -> char* {
    char* p = ws + o; o = (o + bytes + 255) & ~(size_t)255; return p;
  };
  // fixed region (live across the whole call)
  u16* wte_b     = (u16*)alloc((size_t)HV*HE*2);        // 77.2 MB
  u16* hid_b     = (u16*)alloc((size_t)HBL*HE*2);       // 1.6 MB
  float* cprob   = (float*)alloc((size_t)HBL*HM*4);     // 1.6 MB
  float* rowpart = (float*)alloc((size_t)HBL*NTILES*4); // 1.6 MB
  float* gatev   = (float*)alloc(HBL*4);

  // expl (bf16 exp of logits) aliases the mid-phase union region: every union
  // buffer is dead before the big GEMM writes expl (multihop runs first).
  const bool bigws = ws_size >= (size_t)196*1024*1024;
  u16* expl = (u16*)(ws + o);                           // 103.0 MB if bigws
  // union region (same offset as expl)
  u16* wcat  = (u16*)alloc((size_t)HE*2*HE*2);          // 2.4 MB
  u16* wr1   = (u16*)alloc((size_t)HE*HE*2);            // 1.2 MB
  u16* wt_b  = (u16*)alloc((size_t)HE*3*HE*2);          // 3.5 MB
  u16* rel_b = (u16*)alloc((size_t)40*HE*2);
  u16* anode = (u16*)alloc((size_t)HB*HM*2*HE*2);       // 9.8 MB
  u16* nodeb = (u16*)alloc((size_t)HB*HM*HE*2);         // 4.9 MB
  u16* relWr = (u16*)alloc((size_t)40*HE*2);
  float* scores = (float*)alloc((size_t)HB*HL*840*4);   // 3.4 MB
  u16* P13   = (u16*)alloc((size_t)HB*840*HE*2);        // 10.3 MB
  (void)in_sizes; (void)n_in; (void)out_size;

  // 1. small preprocessing (fused)
  prep_k<<<5406, 256, 0, stream>>>(hs, rel, Wr + (size_t)HE*HE, Wt,
      Ws + (size_t)HE*HE, Wn + (size_t)HE*HE, hid_b, rel_b, wr1, wt_b, wcat);

  // 2. fused GCN scatter -> anode (bf16 [8][400][1536])
  gcn_scatter_k<<<HB*48, 256, 0, stream>>>(wte, rel, cids, rids, head, tail, anode);

  // 3. node = relu(anode @ wcat^T): batched, M=400, N=768, K=1536
  gemm_bt<1,1,0><<<dim3(4,6,8), 256, 0, stream>>>(anode, wcat, nodeb, nullptr,
      HM, HE, 2*HE, 2*HE, 2*HE, HE, (long)HM*2*HE, 0, (long)HM*HE);
  // 4. relWr = rel @ Wr1^T  (40x768, K=768)
  gemm_bt<0,1,0><<<dim3(1,6,1), 256, 0, stream>>>(rel_b, wr1, relWr, nullptr,
      40, HE, HE, HE, HE, HE, 0, 0, 0);
  // 5. relW2 = relWr @ Wt2^T, broadcast into all 8 batch slots of P13[800..839]
  gemm_bt<0,1,0><<<dim3(1,6,8), 256, 0, stream>>>(relWr, wt_b + HE,
      P13 + (long)800*HE, nullptr,
      40, HE, HE, HE, 3*HE, HE, 0, 0, (long)840*HE);
  // 6/7. P1 = node @ Wt1^T -> P13 rows 0..399 ; P3 = node @ Wt3^T -> 400..799
  gemm_bt<0,1,0><<<dim3(4,6,8), 256, 0, stream>>>(nodeb, wt_b, P13, nullptr,
      HM, HE, HE, HE, 3*HE, HE, (long)HM*HE, 0, (long)840*HE);
  gemm_bt<0,1,0><<<dim3(4,6,8), 256, 0, stream>>>(nodeb, wt_b + 2*HE,
      P13 + (long)HM*HE, nullptr,
      HM, HE, HE, HE, 3*HE, HE, (long)HM*HE, 0, (long)840*HE);
  // 8. scores = hid @ P13^T: batched, M=128, N=840, K=768
  gemm_bt<0,0,0><<<dim3(1,7,8), 256, 0, stream>>>(hid_b, P13, scores, nullptr,
      HL, 840, HE, HE, HE, 840, (long)HL*HE, (long)840*HE, (long)HL*840);

  // 9. multi-hop + gate (consumes scores -> union region becomes dead)
  multihop_k<<<HBL, 256, 0, stream>>>(scores, hs, gw, gb, head, tail, rids,
      labels, dist, gatev, cprob);

  // 10. wte -> bf16 right before the big GEMM (L3 residency)
  cvt4_k<<<4096, 256, 0, stream>>>(wte, wte_b, (long)HV*HE/4);

  // 11. exp(hid @ wte^T) + rowsum partials. Grid 3144 = 8 XCDs x 393 n-tiles.
  if (bigws) {
    gemm_bt<0,1,1><<<3144, 256, 0, stream>>>(hid_b, wte_b, expl, rowpart,
        HBL, HV, HE, HE, HE, ELD, 0, 0, 0);
    finalize_k<1><<<HBL*13, 256, 0, stream>>>(expl, rowpart, gatev, cprob,
        vmap, mmask, out);
  } else {
    gemm_bt<0,0,1><<<3144, 256, 0, stream>>>(hid_b, wte_b, out, rowpart,
        HBL, HV, HE, HE, HE, HV, 0, 0, 0);
    finalize_k<0><<<HBL*13, 256, 0, stream>>>(out, rowpart, gatev, cprob,
        vmap, mmask, out);
  }
}

// Round 5
// 461.634 us; speedup vs baseline: 1.4440x; 1.1681x over previous
//
#include <hip/hip_runtime.h>
#include <stdint.h>

#define HB 8
#define HL 128
#define HV 50257
#define HE 768
#define HM 400
#define HMT 800
#define HBL (HB*HL)
#define NTILES 393   // ceil(HV/128)
#define ELD 50272    // padded bf16-exp leading dim (mult of 16)

typedef __attribute__((ext_vector_type(4))) float f32x4;
typedef __attribute__((ext_vector_type(8))) short bf16x8;
typedef unsigned short u16;

struct u16x4 { u16 x, y, z, w; };

__device__ __forceinline__ u16 f2bf(float x){
  union { float f; uint32_t u; } v; v.f = x;
  uint32_t r = v.u + 0x7fffu + ((v.u >> 16) & 1u);
  return (u16)(r >> 16);
}
__device__ __forceinline__ float bf2f(u16 b){
  union { uint32_t u; float f; } v; v.u = ((uint32_t)b) << 16;
  return v.f;
}
__device__ __forceinline__ void glds(const u16* g, const u16* l){
  __builtin_amdgcn_global_load_lds(
      (const __attribute__((address_space(1))) void*)g,
      (__attribute__((address_space(3))) void*)l, 16, 0, 0);
}

// ---- big conversion (wte) ---------------------------------------------------
__global__ __launch_bounds__(256) void cvt4_k(const float* __restrict__ src,
                                              u16* __restrict__ dst, long n4){
  long i = (long)blockIdx.x * 256 + threadIdx.x;
  long stride = (long)gridDim.x * 256;
  for (; i < n4; i += stride) {
    const float4 x = ((const float4*)src)[i];
    u16x4 y; y.x = f2bf(x.x); y.y = f2bf(x.y); y.z = f2bf(x.z); y.w = f2bf(x.w);
    ((u16x4*)dst)[i] = y;
  }
}

// ---- fused small preprocessing: hid, rel, Wr1, Wt, wcat, vmm ---------------
__global__ __launch_bounds__(256) void prep_k(const float* __restrict__ hs,
    const float* __restrict__ rel, const float* __restrict__ Wr1src,
    const float* __restrict__ Wtsrc, const float* __restrict__ Ws1,
    const float* __restrict__ Wn1, const int* __restrict__ vmap,
    const int* __restrict__ mmask, u16* __restrict__ hid_b, u16* __restrict__ rel_b,
    u16* __restrict__ wr1, u16* __restrict__ wt_b, u16* __restrict__ wcat,
    int* __restrict__ vmm){
  const int b = blockIdx.x, t = threadIdx.x;
  if (b < 768) {
    int i = b*256 + t;
    float4 x = ((const float4*)hs)[i];
    u16x4 y; y.x=f2bf(x.x); y.y=f2bf(x.y); y.z=f2bf(x.z); y.w=f2bf(x.w);
    ((u16x4*)hid_b)[i] = y;
  } else if (b < 798) {
    int i = (b-768)*256 + t;
    float4 x = ((const float4*)rel)[i];
    u16x4 y; y.x=f2bf(x.x); y.y=f2bf(x.y); y.z=f2bf(x.z); y.w=f2bf(x.w);
    ((u16x4*)rel_b)[i] = y;
  } else if (b < 1374) {
    int i = (b-798)*256 + t;
    float4 x = ((const float4*)Wr1src)[i];
    u16x4 y; y.x=f2bf(x.x); y.y=f2bf(x.y); y.z=f2bf(x.z); y.w=f2bf(x.w);
    ((u16x4*)wr1)[i] = y;
  } else if (b < 3102) {
    int i = (b-1374)*256 + t;
    float4 x = ((const float4*)Wtsrc)[i];
    u16x4 y; y.x=f2bf(x.x); y.y=f2bf(x.y); y.z=f2bf(x.z); y.w=f2bf(x.w);
    ((u16x4*)wt_b)[i] = y;
  } else if (b < 5406) {
    int i = (b-3102)*256 + t;
    int e = i / HE, k = i - e*HE;
    wcat[(long)e*(2*HE) + k]      = f2bf(Ws1[i]);
    wcat[(long)e*(2*HE) + HE + k] = f2bf(Wn1[i]);
  } else {
    int base = (b-5406)*1024 + t*4;
    #pragma unroll
    for (int i = 0; i < 4; ++i) {
      int c = base + i;
      if (c < HV) vmm[c] = mmask[c] ? vmap[c] : -1;
    }
  }
}

// ---- fused GCN scatter + anode build (per batch x 16-col chunk) ------------
__global__ __launch_bounds__(256) void gcn_scatter_k(const float* __restrict__ wte,
    const float* __restrict__ rel, const int* __restrict__ cids,
    const int* __restrict__ rids, const int* __restrict__ head,
    const int* __restrict__ tail, u16* __restrict__ An){
  const int ch = blockIdx.x % 48;
  const int b  = blockIdx.x / 48;
  const int e0 = ch * 16;
  __shared__ float cw[HM][17];
  __shared__ float upd[HM][17];
  __shared__ float relc[40][17];
  __shared__ float cnt[HM];
  const int tid = threadIdx.x;

  for (int idx = tid; idx < HM*16; idx += 256) {
    int m = idx >> 4, e = idx & 15;
    cw[m][e] = wte[(long)cids[b*HM+m]*HE + e0 + e];
    upd[m][e] = 0.f;
  }
  for (int idx = tid; idx < 40*16; idx += 256) {
    int r = idx >> 4, e = idx & 15;
    relc[r][e] = rel[r*HE + e0 + e];
  }
  for (int m = tid; m < HM; m += 256) cnt[m] = 0.f;
  __syncthreads();

  for (int j = tid; j < HMT; j += 256) {
    int h = head[b*HMT+j], t = tail[b*HMT+j], r = rids[b*HMT+j];
    atomicAdd(&cnt[t], 1.f);
    atomicAdd(&cnt[h], 1.f);
    #pragma unroll
    for (int e = 0; e < 16; ++e) {
      float rv = relc[r][e];
      atomicAdd(&upd[t][e], cw[h][e] - rv);
      atomicAdd(&upd[h][e], cw[t][e] - rv);
    }
  }
  __syncthreads();

  for (int idx = tid; idx < HM*16; idx += 256) {
    int m = idx >> 4, e = idx & 15;
    float ic = 1.f / fmaxf(cnt[m], 1.f);
    u16* dst = An + ((long)b*HM + m) * (2*HE);
    dst[e0 + e]      = f2bf(cw[m][e]);
    dst[HE + e0 + e] = f2bf(upd[m][e] * ic);
  }
}

// ---- generic MFMA GEMM: C[M,N] = act(A[M,K] @ B[N,K]^T) ---------------------
// 128x128 tile, BK=64, XOR-swizzled LDS (16B slot ^ row&7), 4 waves 2x2,
// 16x16x32 bf16 MFMA, global_load_lds (linear dest + inverse-swizzled source).
// BIG=1: 1-D grid 3144 = 8 XCD chunks of 393, exp+bf16(or f32) store + rowpart.
// DUALB=1: grid.z=16; z<8 uses Bm,C+0 (batch z); z>=8 uses Bm2,C+Coff2 (batch z-8).
template<int ACT, int OUTBF16, int BIG, int DUALB>
__global__ __launch_bounds__(256) void gemm_bt(
    const u16* __restrict__ A, const u16* __restrict__ Bm,
    const u16* __restrict__ Bm2, void* __restrict__ Cout,
    float* __restrict__ rowpart,
    int Mdim, int Ndim, int Kdim, int lda, int ldb, int ldc,
    long Abs, long Bbs, long Cbs, long Coff2)
{
  __shared__ alignas(16) u16 Asm[128*64];
  __shared__ alignas(16) u16 Bsm[128*64];
  int mtile, ntile, bz;
  if (BIG) {
    const int wg = (blockIdx.x & 7) * NTILES + (blockIdx.x >> 3);
    mtile = wg & 7; ntile = wg >> 3; bz = 0;
  } else {
    mtile = blockIdx.x; ntile = blockIdx.y; bz = blockIdx.z;
  }
  const int zb = DUALB ? (bz & 7) : bz;
  const bool alt = DUALB && (bz >= 8);
  const u16* Ab = A + (long)zb * Abs;
  const u16* Bb = (alt ? Bm2 : Bm) + (long)zb * Bbs;
  const int m0 = mtile * 128;
  const int n0 = ntile * 128;
  const int tid = threadIdx.x;
  const int lane = tid & 63;
  const int wid = tid >> 6;
  const int wr = wid >> 1, wc = wid & 1;
  const int srw = lane >> 3;      // row within 8-row chunk
  const int sl  = lane & 7;       // 16B slot within 128B row

  f32x4 acc[4][4] = {};

  for (int k0 = 0; k0 < Kdim; k0 += 64) {
    #pragma unroll
    for (int i = 0; i < 4; ++i) {
      const int c = i*4 + wid;                 // chunk 0..15 (8 rows each)
      const int row = c*8 + srw;               // 0..127
      const int koff = k0 + ((sl ^ srw) * 8);  // inverse-swizzled source
      int ra = m0 + row; if (ra > Mdim-1) ra = Mdim-1;
      glds(Ab + (long)ra * lda + koff, &Asm[c*512]);
      int rn = n0 + row; if (rn > Ndim-1) rn = Ndim-1;
      glds(Bb + (long)rn * ldb + koff, &Bsm[c*512]);
    }
    __syncthreads();
    #pragma unroll
    for (int kk = 0; kk < 2; ++kk) {
      bf16x8 af[4], bfr[4];
      #pragma unroll
      for (int mi = 0; mi < 4; ++mi) {
        const int R = wr*64 + mi*16 + (lane & 15);
        af[mi] = *(const bf16x8*)&Asm[R*64 + (((kk*4 + (lane>>4)) ^ (R & 7)) * 8)];
      }
      #pragma unroll
      for (int ni = 0; ni < 4; ++ni) {
        const int R = wc*64 + ni*16 + (lane & 15);
        bfr[ni] = *(const bf16x8*)&Bsm[R*64 + (((kk*4 + (lane>>4)) ^ (R & 7)) * 8)];
      }
      #pragma unroll
      for (int mi = 0; mi < 4; ++mi)
        #pragma unroll
        for (int ni = 0; ni < 4; ++ni)
          acc[mi][ni] = __builtin_amdgcn_mfma_f32_16x16x32_bf16(af[mi], bfr[ni], acc[mi][ni], 0, 0, 0);
    }
    __syncthreads();
  }

  const int cr0 = m0 + wr*64 + ((lane >> 4) * 4);
  const int cc0 = n0 + wc*64 + (lane & 15);

  if (BIG) {
    // store exp(logit) (bf16 padded / f32), accumulate row partials (atomic-free)
    float* rs = (float*)Asm;
    #pragma unroll
    for (int mi = 0; mi < 4; ++mi) {
      #pragma unroll
      for (int r = 0; r < 4; ++r) {
        const int rowi = cr0 + mi*16 + r;
        float s = 0.f;
        #pragma unroll
        for (int ni = 0; ni < 4; ++ni) {
          const int col = cc0 + ni*16;
          if (col < Ndim) {
            float e = __expf(acc[mi][ni][r]);
            if (OUTBF16) ((u16*)Cout)[(long)rowi*ELD + col] = f2bf(e);
            else        ((float*)Cout)[(long)rowi*HV + col] = e;
            s += e;
          }
        }
        s += __shfl_xor(s, 8); s += __shfl_xor(s, 4);
        s += __shfl_xor(s, 2); s += __shfl_xor(s, 1);
        if ((lane & 15) == 0)
          rs[wc*128 + wr*64 + mi*16 + ((lane >> 4) << 2) + r] = s;
      }
    }
    __syncthreads();
    if (tid < 128)
      rowpart[(long)(m0 + tid) * NTILES + ntile] = rs[tid] + rs[128 + tid];
    return;
  }

  const long cb = (long)zb * Cbs + (alt ? Coff2 : 0);
  #pragma unroll
  for (int mi = 0; mi < 4; ++mi) {
    #pragma unroll
    for (int ni = 0; ni < 4; ++ni) {
      const int col = cc0 + ni*16;
      if (col < Ndim) {
        #pragma unroll
        for (int r = 0; r < 4; ++r) {
          const int rowi = cr0 + mi*16 + r;
          if (rowi < Mdim) {
            float v = acc[mi][ni][r];
            if (ACT == 1) v = fmaxf(v, 0.f);
            if (OUTBF16) ((u16*)Cout)[cb + (long)rowi*ldc + col] = f2bf(v);
            else        ((float*)Cout)[cb + (long)rowi*ldc + col] = v;
          }
        }
      }
    }
  }
}

// ---- multi-hop + gate: factored triple_prob, hops, softmax over M ----------
__global__ __launch_bounds__(256) void multihop_k(const float* __restrict__ scores,
    const float* __restrict__ hs, const float* __restrict__ gw,
    const float* __restrict__ gb,
    const int* __restrict__ head, const int* __restrict__ tail,
    const int* __restrict__ rids, const int* __restrict__ labels,
    const int* __restrict__ dist, float* __restrict__ gatev,
    float* __restrict__ cprob){
  const int bl = blockIdx.x;
  const int b = bl >> 7;
  const int tid = threadIdx.x;
  const int lane = tid & 63, wid = tid >> 6;
  __shared__ float srow[840];
  __shared__ float tp[HMT];
  __shared__ float ns[HM], sacc[HM], tot[HM], invc[HM], dec[HM];
  __shared__ float red[16];
  __shared__ float gred[4];
  const int* hb = head + b*HMT;
  const int* tb = tail + b*HMT;
  const int* rb = rids + b*HMT;
  const int* lb = labels + b*HMT;
  const float* sr = scores + (long)bl * 840;

  float gs = 0.f;
  for (int e = tid; e < HE; e += 256) gs += hs[(long)bl*HE + e] * gw[e];
  for (int o = 32; o; o >>= 1) gs += __shfl_down(gs, o);
  if (lane == 0) gred[wid] = gs;

  for (int i = tid; i < 840; i += 256) srow[i] = sr[i];
  for (int m = tid; m < HM; m += 256) {
    int d = dist[b*HM + m];
    float im = (d == 0) ? 1.f : 0.f;
    ns[m] = im; tot[m] = im * -100000.f;
    dec[m] = (d == 0) ? 1.f : ((d == 1) ? 0.8f : 0.64f);
    sacc[m] = 0.f; invc[m] = 0.f;
  }
  __syncthreads();
  if (tid == 0)
    gatev[bl] = 1.f / (1.f + __expf(-(gred[0]+gred[1]+gred[2]+gred[3] + gb[0])));
  for (int j = tid; j < HMT; j += 256) {
    atomicAdd(&invc[tb[j]], 1.f);
    float x = srow[hb[j]] + srow[400 + tb[j]] + srow[800 + rb[j]];
    tp[j] = (lb[j] == -1) ? 0.f : 1.f / (1.f + __expf(-x));
  }
  __syncthreads();
  for (int m = tid; m < HM; m += 256) invc[m] = 1.f / fmaxf(invc[m], 1.f);
  __syncthreads();

  for (int hop = 0; hop < 2; ++hop) {
    for (int j = tid; j < HMT; j += 256) {
      float u = ns[hb[j]] * 0.8f + tp[j];
      atomicAdd(&sacc[tb[j]], u);
    }
    __syncthreads();
    for (int m = tid; m < HM; m += 256) {
      float v = sacc[m] * invc[m];
      ns[m] = v; tot[m] += v * dec[m]; sacc[m] = 0.f;
    }
    __syncthreads();
  }

  float lmx = -3.4e38f;
  for (int m = tid; m < HM; m += 256) lmx = fmaxf(lmx, tot[m]);
  for (int o = 32; o; o >>= 1) lmx = fmaxf(lmx, __shfl_down(lmx, o));
  if (lane == 0) red[wid] = lmx;
  __syncthreads();
  float gmx = fmaxf(fmaxf(red[0], red[1]), fmaxf(red[2], red[3]));
  float ls = 0.f;
  for (int m = tid; m < HM; m += 256) ls += __expf(tot[m] - gmx);
  for (int o = 32; o; o >>= 1) ls += __shfl_down(ls, o);
  if (lane == 0) red[8 + wid] = ls;
  __syncthreads();
  float inv = 1.f / (red[8] + red[9] + red[10] + red[11]);
  float* outrow = cprob + (long)bl * HM;
  for (int m = tid; m < HM; m += 256) outrow[m] = __expf(tot[m] - gmx) * inv;
}

// ---- finalize: fused rowsum reduce + LDS-gather blend ----------------------
// grid = HBL * 13; per block: one row x 4096-col chunk (2 iters x 8/thread).
template<int EXPBF>
__global__ __launch_bounds__(256) void finalize_k(const void* __restrict__ expl,
    const float* __restrict__ rowpart, const float* __restrict__ gatev,
    const float* __restrict__ cprob, const int* __restrict__ vmm,
    float* __restrict__ out){
  const int r = blockIdx.x / 13;
  const int ch = blockIdx.x - r*13;
  const int tid = threadIdx.x;
  __shared__ float red[4];
  __shared__ float cpl[HM];
  float s = 0.f;
  for (int t = tid; t < NTILES; t += 256) s += rowpart[r*NTILES + t];
  for (int o = 32; o; o >>= 1) s += __shfl_down(s, o);
  if ((tid & 63) == 0) red[tid >> 6] = s;
  const float g = gatev[r];
  for (int m = tid; m < HM; m += 256) cpl[m] = g * cprob[r*HM + m];
  __syncthreads();
  const float scale = (1.f - g) / (red[0] + red[1] + red[2] + red[3]);
  const u16* erb = (const u16*)expl + (long)r * ELD;
  const float* erf = (const float*)expl + (long)r * HV;
  float* orow = out + (long)r * HV;
  #pragma unroll
  for (int it = 0; it < 2; ++it) {
    const int c = ch*4096 + it*2048 + tid*8;
    if (c + 8 <= HV) {
      float e[8];
      if (EXPBF) {
        bf16x8 v = *(const bf16x8*)&erb[c];
        #pragma unroll
        for (int i = 0; i < 8; ++i) e[i] = bf2f((u16)v[i]);
      } else {
        float4 a = *(const float4*)&erf[c];
        float4 b2 = *(const float4*)&erf[c+4];
        e[0]=a.x; e[1]=a.y; e[2]=a.z; e[3]=a.w;
        e[4]=b2.x; e[5]=b2.y; e[6]=b2.z; e[7]=b2.w;
      }
      int4 v0 = *(const int4*)&vmm[c];
      int4 v1 = *(const int4*)&vmm[c+4];
      const int ix[8] = {v0.x, v0.y, v0.z, v0.w, v1.x, v1.y, v1.z, v1.w};
      float o8[8];
      #pragma unroll
      for (int i = 0; i < 8; ++i)
        o8[i] = (ix[i] >= 0 ? cpl[ix[i]] : 0.f) + scale * e[i];
      *(float4*)&orow[c]   = make_float4(o8[0], o8[1], o8[2], o8[3]);
      *(float4*)&orow[c+4] = make_float4(o8[4], o8[5], o8[6], o8[7]);
    } else if (c < HV) {
      for (int i = 0; i < 8 && c + i < HV; ++i) {
        float e = EXPBF ? bf2f(((const u16*)expl)[(long)r*ELD + c + i]) : erf[c+i];
        int ix = vmm[c+i];
        orow[c+i] = (ix >= 0 ? cpl[ix] : 0.f) + scale * e;
      }
    }
  }
}

// ---------------------------------------------------------------------------
extern "C" void kernel_launch(void* const* d_in, const int* in_sizes, int n_in,
                              void* d_out, int out_size, void* d_ws, size_t ws_size,
                              hipStream_t stream)
{
  const float* hs   = (const float*)d_in[0];
  const float* wte  = (const float*)d_in[1];
  const float* rel  = (const float*)d_in[2];
  const float* Ws   = (const float*)d_in[3];
  const float* Wn   = (const float*)d_in[4];
  const float* Wr   = (const float*)d_in[5];
  const float* Wt   = (const float*)d_in[6];
  const float* gw   = (const float*)d_in[7];
  const float* gb   = (const float*)d_in[8];
  const int* cids   = (const int*)d_in[9];
  const int* rids   = (const int*)d_in[10];
  const int* head   = (const int*)d_in[11];
  const int* tail   = (const int*)d_in[12];
  const int* labels = (const int*)d_in[13];
  const int* dist   = (const int*)d_in[14];
  const int* vmap   = (const int*)d_in[15];
  const int* mmask  = (const int*)d_in[16];
  float* out = (float*)d_out;

  char* ws = (char*)d_ws;
  size_t o = 0;
  auto alloc = [&](size_t bytes) -> char* {
    char* p = ws + o; o = (o + bytes + 255) & ~(size_t)255; return p;
  };
  // fixed region (live across the whole call)
  u16* wte_b     = (u16*)alloc((size_t)HV*HE*2);        // 77.2 MB
  u16* hid_b     = (u16*)alloc((size_t)HBL*HE*2);       // 1.6 MB
  float* cprob   = (float*)alloc((size_t)HBL*HM*4);     // 1.6 MB
  float* rowpart = (float*)alloc((size_t)HBL*NTILES*4); // 1.6 MB
  float* gatev   = (float*)alloc(HBL*4);
  int* vmm       = (int*)alloc((size_t)HV*4);           // 0.2 MB

  // expl (bf16 exp of logits) aliases the mid-phase union region: every union
  // buffer is dead before the big GEMM writes expl (multihop runs first).
  const bool bigws = ws_size >= (size_t)196*1024*1024;
  u16* expl = (u16*)(ws + o);                           // 103.0 MB if bigws
  // union region (same offset as expl)
  u16* wcat  = (u16*)alloc((size_t)HE*2*HE*2);          // 2.4 MB
  u16* wr1   = (u16*)alloc((size_t)HE*HE*2);            // 1.2 MB
  u16* wt_b  = (u16*)alloc((size_t)HE*3*HE*2);          // 3.5 MB
  u16* rel_b = (u16*)alloc((size_t)40*HE*2);
  u16* anode = (u16*)alloc((size_t)HB*HM*2*HE*2);       // 9.8 MB
  u16* nodeb = (u16*)alloc((size_t)HB*HM*HE*2);         // 4.9 MB
  u16* relWr = (u16*)alloc((size_t)40*HE*2);
  float* scores = (float*)alloc((size_t)HB*HL*840*4);   // 3.4 MB
  u16* P13   = (u16*)alloc((size_t)HB*840*HE*2);        // 10.3 MB
  (void)in_sizes; (void)n_in; (void)out_size;

  // 1. small preprocessing (fused)
  prep_k<<<5456, 256, 0, stream>>>(hs, rel, Wr + (size_t)HE*HE, Wt,
      Ws + (size_t)HE*HE, Wn + (size_t)HE*HE, vmap, mmask,
      hid_b, rel_b, wr1, wt_b, wcat, vmm);

  // 2. fused GCN scatter -> anode (bf16 [8][400][1536])
  gcn_scatter_k<<<HB*48, 256, 0, stream>>>(wte, rel, cids, rids, head, tail, anode);

  // 3. node = relu(anode @ wcat^T): batched, M=400, N=768, K=1536
  gemm_bt<1,1,0,0><<<dim3(4,6,8), 256, 0, stream>>>(anode, wcat, nullptr, nodeb,
      nullptr, HM, HE, 2*HE, 2*HE, 2*HE, HE, (long)HM*2*HE, 0, (long)HM*HE, 0);
  // 4. relWr = rel @ Wr1^T  (40x768, K=768)
  gemm_bt<0,1,0,0><<<dim3(1,6,1), 256, 0, stream>>>(rel_b, wr1, nullptr, relWr,
      nullptr, 40, HE, HE, HE, HE, HE, 0, 0, 0, 0);
  // 5. relW2 = relWr @ Wt2^T, broadcast into all 8 batch slots of P13[800..839]
  gemm_bt<0,1,0,0><<<dim3(1,6,8), 256, 0, stream>>>(relWr, wt_b + HE, nullptr,
      P13 + (long)800*HE, nullptr,
      40, HE, HE, HE, 3*HE, HE, 0, 0, (long)840*HE, 0);
  // 6+7 fused. z<8: P1 = node @ Wt1^T -> P13 rows 0..399 (batch z);
  //            z>=8: P3 = node @ Wt3^T -> P13 rows 400..799 (batch z-8).
  gemm_bt<0,1,0,1><<<dim3(4,6,16), 256, 0, stream>>>(nodeb, wt_b, wt_b + 2*HE,
      P13, nullptr,
      HM, HE, HE, HE, 3*HE, HE, (long)HM*HE, 0, (long)840*HE, (long)HM*HE);
  // 8. scores = hid @ P13^T: batched, M=128, N=840, K=768
  gemm_bt<0,0,0,0><<<dim3(1,7,8), 256, 0, stream>>>(hid_b, P13, nullptr, scores,
      nullptr, HL, 840, HE, HE, HE, 840, (long)HL*HE, (long)840*HE, (long)HL*840, 0);

  // 9. multi-hop + gate (consumes scores -> union region becomes dead)
  multihop_k<<<HBL, 256, 0, stream>>>(scores, hs, gw, gb, head, tail, rids,
      labels, dist, gatev, cprob);

  // 10. wte -> bf16 right before the big GEMM (L3 residency)
  cvt4_k<<<4096, 256, 0, stream>>>(wte, wte_b, (long)HV*HE/4);

  // 11. exp(hid @ wte^T) + rowsum partials. Grid 3144 = 8 XCDs x 393 n-tiles.
  if (bigws) {
    gemm_bt<0,1,1,0><<<3144, 256, 0, stream>>>(hid_b, wte_b, nullptr, expl,
        rowpart, HBL, HV, HE, HE, HE, ELD, 0, 0, 0, 0);
    finalize_k<1><<<HBL*13, 256, 0, stream>>>(expl, rowpart, gatev, cprob,
        vmm, out);
  } else {
    gemm_bt<0,0,1,0><<<3144, 256, 0, stream>>>(hid_b, wte_b, nullptr, out,
        rowpart, HBL, HV, HE, HE, HE, HV, 0, 0, 0, 0);
    finalize_k<0><<<HBL*13, 256, 0, stream>>>(out, rowpart, gatev, cprob,
        vmm, out);
  }
}